// Round 3
// baseline (763.034 us; speedup 1.0000x reference)
//
#include <hip/hip_runtime.h>
#include <hip/hip_bf16.h>

#define NREL 8
#define CH   64   // IN_CH == HID_CH == 64

static __device__ __forceinline__ unsigned short f2bf(float f) {
    union { float f; unsigned u; } v; v.f = f;
    unsigned r = v.u + 0x7FFF + ((v.u >> 16) & 1);   // round-to-nearest-even
    return (unsigned short)(r >> 16);
}
static __device__ __forceinline__ float bf2f(unsigned short b) {
    union { unsigned u; float f; } v; v.u = ((unsigned)b) << 16;
    return v.f;
}

// ---------------------------------------------------------------------------
// Kernel 1: xw[r][n][h] = sum_i x[n][i] * W[r][i][h], stored as bf16.
// ---------------------------------------------------------------------------
__global__ __launch_bounds__(256) void rgcn_xw_kernel(
    const float* __restrict__ x, const float* __restrict__ W,
    unsigned short* __restrict__ xw, int nN)
{
    __shared__ float xT[64 * 64];   // [i][n]
    __shared__ float wb[64 * 64];   // [i][h]

    const int t      = threadIdx.x;
    const int tile   = blockIdx.x;
    const int r      = blockIdx.y;
    const int n_base = tile * 64;

    // Load W[r]: 4096 floats = 256 threads x 4 float4s, layout [i][h].
    {
        const float* wsrc = W + ((size_t)r << 12);
        #pragma unroll
        for (int j = 0; j < 4; ++j) {
            const int off = (t << 2) + (j << 10);
            *(float4*)(wb + off) = *(const float4*)(wsrc + off);
        }
    }

    // Load x tile transposed. Thread t: node lane n_l = t&63, i-chunk (t>>6)*16.
    {
        const int n_l = t & 63;
        const int i0  = (t >> 6) << 4;
        const int n   = n_base + n_l;
        if (n < nN) {
            const float* xp = x + (size_t)n * CH + i0;
            #pragma unroll
            for (int j = 0; j < 4; ++j) {
                const float4 v = *(const float4*)(xp + j * 4);
                xT[(i0 + j * 4 + 0) * 64 + n_l] = v.x;
                xT[(i0 + j * 4 + 1) * 64 + n_l] = v.y;
                xT[(i0 + j * 4 + 2) * 64 + n_l] = v.z;
                xT[(i0 + j * 4 + 3) * 64 + n_l] = v.w;
            }
        } else {
            #pragma unroll
            for (int j = 0; j < 16; ++j) xT[(i0 + j) * 64 + n_l] = 0.f;
        }
    }
    __syncthreads();

    const int tn = t >> 4;   // node quad
    const int th = t & 15;   // h quad

    float acc[4][4];
    #pragma unroll
    for (int a = 0; a < 4; ++a)
        #pragma unroll
        for (int b = 0; b < 4; ++b) acc[a][b] = 0.f;

    #pragma unroll
    for (int i = 0; i < 64; ++i) {
        const float4 av = *(const float4*)(xT + i * 64 + (tn << 2));
        const float4 bv = *(const float4*)(wb + i * 64 + (th << 2));
        acc[0][0] += av.x * bv.x; acc[0][1] += av.x * bv.y;
        acc[0][2] += av.x * bv.z; acc[0][3] += av.x * bv.w;
        acc[1][0] += av.y * bv.x; acc[1][1] += av.y * bv.y;
        acc[1][2] += av.y * bv.z; acc[1][3] += av.y * bv.w;
        acc[2][0] += av.z * bv.x; acc[2][1] += av.z * bv.y;
        acc[2][2] += av.z * bv.z; acc[2][3] += av.z * bv.w;
        acc[3][0] += av.w * bv.x; acc[3][1] += av.w * bv.y;
        acc[3][2] += av.w * bv.z; acc[3][3] += av.w * bv.w;
    }

    #pragma unroll
    for (int dn = 0; dn < 4; ++dn) {
        const int n = n_base + (tn << 2) + dn;
        if (n < nN) {
            ushort4 o;
            o.x = f2bf(acc[dn][0]); o.y = f2bf(acc[dn][1]);
            o.z = f2bf(acc[dn][2]); o.w = f2bf(acc[dn][3]);
            *(ushort4*)(xw + ((size_t)r * nN + n) * CH + (th << 2)) = o;
        }
    }
}

// ---------------------------------------------------------------------------
// Kernel A: histogram of dst.
// ---------------------------------------------------------------------------
__global__ __launch_bounds__(256) void rgcn_hist_kernel(
    const int* __restrict__ ei, int* __restrict__ counts, int nE, int nT)
{
    for (int e = blockIdx.x * 256 + threadIdx.x; e < nE; e += nT)
        atomicAdd(&counts[ei[nE + e]], 1);
}

// ---------------------------------------------------------------------------
// Kernel B: exclusive prefix scan of counts -> start[0..nN], cursor copy.
// Single block, 1024 threads, chunked.
// ---------------------------------------------------------------------------
__global__ __launch_bounds__(1024) void rgcn_scan_kernel(
    const int* __restrict__ counts, int* __restrict__ start,
    int* __restrict__ cursor, int nN)
{
    __shared__ int ssum[1024];
    const int t  = threadIdx.x;
    const int C  = (nN + 1023) >> 10;
    const int lo = t * C;
    const int hi = min(lo + C, nN);

    int s = 0;
    for (int i = lo; i < hi; ++i) s += counts[i];
    ssum[t] = s;
    __syncthreads();

    for (int off = 1; off < 1024; off <<= 1) {
        int add = (t >= off) ? ssum[t - off] : 0;
        __syncthreads();
        ssum[t] += add;
        __syncthreads();
    }

    int run = ssum[t] - s;   // exclusive base for this chunk
    for (int i = lo; i < hi; ++i) {
        start[i]  = run;
        cursor[i] = run;
        run += counts[i];
    }
    if (t == 1023) start[nN] = ssum[1023];
}

// ---------------------------------------------------------------------------
// Kernel C: reorder edges into dst buckets, packing (rel<<28)|src.
// ---------------------------------------------------------------------------
__global__ __launch_bounds__(256) void rgcn_reorder_kernel(
    const int* __restrict__ ei, const int* __restrict__ rel,
    int* __restrict__ cursor, unsigned* __restrict__ sorted, int nE, int nT)
{
    for (int e = blockIdx.x * 256 + threadIdx.x; e < nE; e += nT) {
        const int dst = ei[nE + e];
        const int pos = atomicAdd(&cursor[dst], 1);
        sorted[pos] = ((unsigned)rel[e] << 28) | (unsigned)ei[e];
    }
}

// ---------------------------------------------------------------------------
// Kernel D: one wave per dst node, lane = channel. No atomics.
// ---------------------------------------------------------------------------
__global__ __launch_bounds__(256) void rgcn_gather_kernel(
    const unsigned short* __restrict__ xw, const int* __restrict__ start,
    const unsigned* __restrict__ sorted, float* __restrict__ out, int nN)
{
    const int w    = (int)((blockIdx.x * 256u + threadIdx.x) >> 6);
    const int lane = threadIdx.x & 63;
    if (w >= nN) return;

    const int s   = start[w];
    const int end = start[w + 1];
    float acc = 0.f;

    int e = s;
    for (; e + 1 < end; e += 2) {
        const unsigned c0 = sorted[e];
        const unsigned c1 = sorted[e + 1];
        const float v0 = bf2f(xw[((size_t)(c0 >> 28) * nN + (c0 & 0x0FFFFFFFu)) * CH + lane]);
        const float v1 = bf2f(xw[((size_t)(c1 >> 28) * nN + (c1 & 0x0FFFFFFFu)) * CH + lane]);
        acc += v0;
        acc += v1;
    }
    if (e < end) {
        const unsigned c0 = sorted[e];
        acc += bf2f(xw[((size_t)(c0 >> 28) * nN + (c0 & 0x0FFFFFFFu)) * CH + lane]);
    }

    out[(size_t)w * CH + lane] = acc;
}

// ---------------------------------------------------------------------------
// Fallback (ws too small): compute x[src] @ W[rel] per edge directly.
// ---------------------------------------------------------------------------
__global__ __launch_bounds__(256) void rgcn_direct_kernel(
    const float* __restrict__ x, const float* __restrict__ W,
    const int* __restrict__ ei, const int* __restrict__ rel,
    float* __restrict__ out, int nE, int nWaves)
{
    const int w    = (int)((blockIdx.x * 256u + threadIdx.x) >> 6);
    const int lane = threadIdx.x & 63;

    for (int e = w; e < nE; e += nWaves) {
        const int src = ei[e];
        const int dst = ei[nE + e];
        const int r   = rel[e];
        const float* xrow = x + (size_t)src * CH;
        const float* wcol = W + ((size_t)r << 12) + lane;
        float acc = 0.f;
        #pragma unroll
        for (int i = 0; i < CH; ++i) acc += xrow[i] * wcol[i * CH];
        atomicAdd(out + (size_t)dst * CH + lane, acc);
    }
}

static inline size_t align256(size_t v) { return (v + 255) & ~(size_t)255; }

extern "C" void kernel_launch(void* const* d_in, const int* in_sizes, int n_in,
                              void* d_out, int out_size, void* d_ws, size_t ws_size,
                              hipStream_t stream) {
    const float* x   = (const float*)d_in[0];
    const float* W   = (const float*)d_in[1];
    const int*   ei  = (const int*)d_in[2];
    const int*   rel = (const int*)d_in[3];
    float*       out = (float*)d_out;

    const int nN = in_sizes[0] / CH;   // 50000
    const int nE = in_sizes[3];        // 1000000

    // Harness poisons d_out once and never re-zeroes: clear it every call.
    hipMemsetAsync(out, 0, (size_t)out_size * sizeof(float), stream);

    // Workspace layout
    const size_t sz_xw     = align256((size_t)NREL * nN * CH * sizeof(unsigned short));
    const size_t sz_counts = align256((size_t)(nN + 1) * sizeof(int));
    const size_t sz_start  = align256((size_t)(nN + 1) * sizeof(int));
    const size_t sz_cursor = align256((size_t)(nN + 1) * sizeof(int));
    const size_t sz_sorted = align256((size_t)nE * sizeof(unsigned));
    const size_t need = sz_xw + sz_counts + sz_start + sz_cursor + sz_sorted;

    if (ws_size >= need) {
        char* p = (char*)d_ws;
        unsigned short* xw     = (unsigned short*)p;           p += sz_xw;
        int*            counts = (int*)p;                      p += sz_counts;
        int*            start  = (int*)p;                      p += sz_start;
        int*            cursor = (int*)p;                      p += sz_cursor;
        unsigned*       sorted = (unsigned*)p;

        hipMemsetAsync(counts, 0, (size_t)(nN + 1) * sizeof(int), stream);

        dim3 grid_xw((nN + 63) / 64, NREL);
        rgcn_xw_kernel<<<grid_xw, 256, 0, stream>>>(x, W, xw, nN);

        const int hb = 1024;
        rgcn_hist_kernel<<<hb, 256, 0, stream>>>(ei, counts, nE, hb * 256);
        rgcn_scan_kernel<<<1, 1024, 0, stream>>>(counts, start, cursor, nN);
        rgcn_reorder_kernel<<<hb, 256, 0, stream>>>(ei, rel, cursor, sorted, nE, hb * 256);

        const int gb = (nN * 64 + 255) / 256;
        rgcn_gather_kernel<<<gb, 256, 0, stream>>>(xw, start, sorted, out, nN);
    } else {
        const int blocks = 2048;
        const int nWaves = blocks * (256 / 64);
        rgcn_direct_kernel<<<blocks, 256, 0, stream>>>(x, W, ei, rel, out, nE, nWaves);
    }
}

// Round 4
// 262.305 us; speedup vs baseline: 2.9090x; 2.9090x over previous
//
#include <hip/hip_runtime.h>
#include <hip/hip_bf16.h>

#define NREL 8
#define CH   64   // IN_CH == HID_CH == 64

typedef unsigned int uint32;

// ---- bf16 helpers (RNE) ----------------------------------------------------
static __device__ __forceinline__ uint32 packbf(float a, float b) {
    uint32 ua = __float_as_uint(a), ub = __float_as_uint(b);
    ua = (ua + 0x7fffu + ((ua >> 16) & 1u)) >> 16;          // low half  (elem 0)
    ub = (ub + 0x7fffu + ((ub >> 16) & 1u)) & 0xffff0000u;  // high half (elem 1)
    return ua | ub;
}
static __device__ __forceinline__ float bflo(uint32 w) { return __uint_as_float(w << 16); }
static __device__ __forceinline__ float bfhi(uint32 w) { return __uint_as_float(w & 0xffff0000u); }

// ---------------------------------------------------------------------------
// Histogram over key = dst*8 + rel  (counts live in `start`, pre-zeroed)
// ---------------------------------------------------------------------------
__global__ __launch_bounds__(256) void hist_k(
    const int* __restrict__ ei, const int* __restrict__ rel,
    int* __restrict__ cnt, int nE, int nT)
{
    for (int e = blockIdx.x * 256 + threadIdx.x; e < nE; e += nT)
        atomicAdd(&cnt[ei[nE + e] * NREL + rel[e]], 1);
}

// ---------------------------------------------------------------------------
// Multi-block exclusive scan: (1) per-block scan in place + block totals,
// (2) scan of totals, (3) add offsets + fill cursor + start[nK].
// ---------------------------------------------------------------------------
__global__ __launch_bounds__(1024) void scan1_k(
    int* __restrict__ start, int* __restrict__ partials, int nK)
{
    __shared__ int sh[1024];
    const int t = threadIdx.x;
    const int g = blockIdx.x * 1024 + t;
    const int v = (g < nK) ? start[g] : 0;
    sh[t] = v; __syncthreads();
    for (int off = 1; off < 1024; off <<= 1) {
        int add = (t >= off) ? sh[t - off] : 0;
        __syncthreads();
        sh[t] += add;
        __syncthreads();
    }
    start[g] = sh[t] - v;                       // exclusive within block (pad region harmless)
    if (t == 1023) partials[blockIdx.x] = sh[1023];
}

__global__ __launch_bounds__(512) void scan2_k(int* __restrict__ partials, int nP)
{
    __shared__ int sh[512];
    const int t = threadIdx.x;
    const int v = (t < nP) ? partials[t] : 0;
    sh[t] = v; __syncthreads();
    for (int off = 1; off < 512; off <<= 1) {
        int add = (t >= off) ? sh[t - off] : 0;
        __syncthreads();
        sh[t] += add;
        __syncthreads();
    }
    if (t < nP) partials[t] = sh[t] - v;        // exclusive
}

__global__ __launch_bounds__(1024) void scan3_k(
    int* __restrict__ start, const int* __restrict__ partials,
    int* __restrict__ cursor, int nK)
{
    const int g = blockIdx.x * 1024 + threadIdx.x;
    if (g <= nK) {
        const int s = start[g] + partials[blockIdx.x];
        start[g] = s;
        if (g < nK) cursor[g] = s;
    }
}

// ---------------------------------------------------------------------------
// Reorder: sorted[pos] = src, bucketed by key.
// ---------------------------------------------------------------------------
__global__ __launch_bounds__(256) void reorder_k(
    const int* __restrict__ ei, const int* __restrict__ rel,
    int* __restrict__ cursor, int* __restrict__ sorted, int nE, int nT)
{
    for (int e = blockIdx.x * 256 + threadIdx.x; e < nE; e += nT) {
        const int key = ei[nE + e] * NREL + rel[e];
        const int pos = atomicAdd(&cursor[key], 1);
        sorted[pos] = ei[e];
    }
}

// ---------------------------------------------------------------------------
// Aggregate: A[k][ch] = sum over bucket k of x[src][ch], bf16 packed in uint.
// Half-wave (32 lanes) per bucket, lane = channel pair. Wave stores 256 B
// contiguous (two adjacent bucket rows) in one dword instruction.
// ---------------------------------------------------------------------------
__global__ __launch_bounds__(256) void agg_k(
    const float* __restrict__ x, const int* __restrict__ start,
    const int* __restrict__ sorted, uint32* __restrict__ A, int nK)
{
    const int gw   = (int)((blockIdx.x * 256u + threadIdx.x) >> 6);
    const int half = (threadIdx.x >> 5) & 1;
    const int l32  = threadIdx.x & 31;
    const int k    = gw * 2 + half;
    if (k >= nK) return;

    const int s = start[k];
    const int e = start[k + 1];
    float a0 = 0.f, a1 = 0.f;
    for (int j = s; j < e; ++j) {
        const float2 v = *(const float2*)(x + (size_t)sorted[j] * CH + l32 * 2);
        a0 += v.x; a1 += v.y;
    }
    A[(size_t)k * 32 + l32] = packbf(a0, a1);
}

// ---------------------------------------------------------------------------
// GEMM: out[nN,64] = A[nN,512](bf16) @ Wf[512,64](fp32, == W viewed flat).
// 64x64 output tile per block, K staged in chunks of 128. LDS 64 KB.
// ---------------------------------------------------------------------------
__global__ __launch_bounds__(256, 2) void gemm_k(
    const uint32* __restrict__ A, const float* __restrict__ Wf,
    float* __restrict__ out, int nN)
{
    __shared__ float AT[128 * 64];   // [k][n] 32 KB
    __shared__ float WC[128 * 64];   // [k][h] 32 KB

    const int t      = threadIdx.x;
    const int n_base = blockIdx.x * 64;
    const int n_l    = t & 63;
    const int q      = t >> 6;            // 0..3 -> k sub-block of 32
    const int tn     = t >> 4;            // 0..15 node quad
    const int th     = t & 15;            // 0..15 h quad

    float acc[4][4];
    #pragma unroll
    for (int a = 0; a < 4; ++a)
        #pragma unroll
        for (int b = 0; b < 4; ++b) acc[a][b] = 0.f;

    for (int kc = 0; kc < 512; kc += 128) {
        // --- stage A chunk: node n_l, k = kc + q*32 .. +32 (64 B contiguous/lane)
        {
            const int n  = n_base + n_l;
            const int kb = q * 32;
            if (n < nN) {
                const uint32* ap = A + (size_t)n * 256 + ((kc + kb) >> 1);
                #pragma unroll
                for (int m = 0; m < 4; ++m) {
                    const uint4 u = *(const uint4*)(ap + m * 4);   // 8 bf16
                    const int kk = kb + m * 8;
                    AT[(kk + 0) * 64 + n_l] = bflo(u.x);
                    AT[(kk + 1) * 64 + n_l] = bfhi(u.x);
                    AT[(kk + 2) * 64 + n_l] = bflo(u.y);
                    AT[(kk + 3) * 64 + n_l] = bfhi(u.y);
                    AT[(kk + 4) * 64 + n_l] = bflo(u.z);
                    AT[(kk + 5) * 64 + n_l] = bfhi(u.z);
                    AT[(kk + 6) * 64 + n_l] = bflo(u.w);
                    AT[(kk + 7) * 64 + n_l] = bfhi(u.w);
                }
            } else {
                #pragma unroll
                for (int m = 0; m < 32; ++m) AT[(kb + m) * 64 + n_l] = 0.f;
            }
        }
        // --- stage W chunk: 8192 floats from Wf + kc*64, contiguous float4s
        {
            const float* wsrc = Wf + (kc << 6);
            #pragma unroll
            for (int j = 0; j < 8; ++j) {
                const int idx = (t << 2) + (j << 10);
                *(float4*)(WC + idx) = *(const float4*)(wsrc + idx);
            }
        }
        __syncthreads();

        #pragma unroll 8
        for (int i = 0; i < 128; ++i) {
            const float4 av = *(const float4*)(AT + i * 64 + (tn << 2));
            const float4 bv = *(const float4*)(WC + i * 64 + (th << 2));
            acc[0][0] += av.x * bv.x; acc[0][1] += av.x * bv.y;
            acc[0][2] += av.x * bv.z; acc[0][3] += av.x * bv.w;
            acc[1][0] += av.y * bv.x; acc[1][1] += av.y * bv.y;
            acc[1][2] += av.y * bv.z; acc[1][3] += av.y * bv.w;
            acc[2][0] += av.z * bv.x; acc[2][1] += av.z * bv.y;
            acc[2][2] += av.z * bv.z; acc[2][3] += av.z * bv.w;
            acc[3][0] += av.w * bv.x; acc[3][1] += av.w * bv.y;
            acc[3][2] += av.w * bv.z; acc[3][3] += av.w * bv.w;
        }
        __syncthreads();
    }

    #pragma unroll
    for (int dn = 0; dn < 4; ++dn) {
        const int n = n_base + (tn << 2) + dn;
        if (n < nN) {
            float4 o;
            o.x = acc[dn][0]; o.y = acc[dn][1]; o.z = acc[dn][2]; o.w = acc[dn][3];
            *(float4*)(out + (size_t)n * CH + (th << 2)) = o;
        }
    }
}

// ---------------------------------------------------------------------------
// Fallback (ws too small): per-edge direct with atomics.
// ---------------------------------------------------------------------------
__global__ __launch_bounds__(256) void rgcn_direct_kernel(
    const float* __restrict__ x, const float* __restrict__ W,
    const int* __restrict__ ei, const int* __restrict__ rel,
    float* __restrict__ out, int nE, int nWaves)
{
    const int w    = (int)((blockIdx.x * 256u + threadIdx.x) >> 6);
    const int lane = threadIdx.x & 63;

    for (int e = w; e < nE; e += nWaves) {
        const int src = ei[e];
        const int dst = ei[nE + e];
        const int r   = rel[e];
        const float* xrow = x + (size_t)src * CH;
        const float* wcol = W + ((size_t)r << 12) + lane;
        float acc = 0.f;
        #pragma unroll
        for (int i = 0; i < CH; ++i) acc += xrow[i] * wcol[i * CH];
        atomicAdd(out + (size_t)dst * CH + lane, acc);
    }
}

static inline size_t align256(size_t v) { return (v + 255) & ~(size_t)255; }

extern "C" void kernel_launch(void* const* d_in, const int* in_sizes, int n_in,
                              void* d_out, int out_size, void* d_ws, size_t ws_size,
                              hipStream_t stream) {
    const float* x   = (const float*)d_in[0];
    const float* W   = (const float*)d_in[1];
    const int*   ei  = (const int*)d_in[2];
    const int*   rel = (const int*)d_in[3];
    float*       out = (float*)d_out;

    const int nN = in_sizes[0] / CH;   // 50000
    const int nE = in_sizes[3];        // 1000000
    const int nK = nN * NREL;          // 400000
    const int S1B = (nK + 1023) / 1024;   // scan blocks (391)

    // Workspace layout
    const size_t sz_A      = align256((size_t)nK * 32 * sizeof(uint32));        // 51.2 MB bf16
    const size_t sz_start  = align256((size_t)(nK + 1024) * sizeof(int));
    const size_t sz_cursor = align256((size_t)(nK + 1) * sizeof(int));
    const size_t sz_sorted = align256((size_t)nE * sizeof(int));
    const size_t sz_part   = align256(512 * sizeof(int));
    const size_t need = sz_A + sz_start + sz_cursor + sz_sorted + sz_part;

    if (ws_size >= need && S1B <= 512) {
        char* p = (char*)d_ws;
        uint32* A      = (uint32*)p;  p += sz_A;
        int*    start  = (int*)p;     p += sz_start;
        int*    cursor = (int*)p;     p += sz_cursor;
        int*    sorted = (int*)p;     p += sz_sorted;
        int*    part   = (int*)p;

        hipMemsetAsync(start, 0, sz_start, stream);

        const int sb = 1024;
        hist_k<<<sb, 256, 0, stream>>>(ei, rel, start, nE, sb * 256);
        scan1_k<<<S1B, 1024, 0, stream>>>(start, part, nK);
        scan2_k<<<1, 512, 0, stream>>>(part, S1B);
        scan3_k<<<S1B, 1024, 0, stream>>>(start, part, cursor, nK);
        reorder_k<<<sb, 256, 0, stream>>>(ei, rel, cursor, sorted, nE, sb * 256);

        const int aggBlocks = (nK / 2 + 3) / 4;    // 2 buckets/wave, 4 waves/block
        agg_k<<<aggBlocks, 256, 0, stream>>>(x, start, sorted, A, nK);

        gemm_k<<<(nN + 63) / 64, 256, 0, stream>>>(A, W, out, nN);
    } else {
        hipMemsetAsync(out, 0, (size_t)out_size * sizeof(float), stream);
        const int blocks = 2048;
        const int nWaves = blocks * (256 / 64);
        rgcn_direct_kernel<<<blocks, 256, 0, stream>>>(x, W, ei, rel, out, nE, nWaves);
    }
}

// Round 5
// 261.185 us; speedup vs baseline: 2.9214x; 1.0043x over previous
//
#include <hip/hip_runtime.h>
#include <hip/hip_bf16.h>

#define NREL 8
#define CH   64   // IN_CH == HID_CH == 64

typedef unsigned int uint32;

// ---- bf16 helpers (RNE) ----------------------------------------------------
static __device__ __forceinline__ uint32 packbf(float a, float b) {
    uint32 ua = __float_as_uint(a), ub = __float_as_uint(b);
    ua = (ua + 0x7fffu + ((ua >> 16) & 1u)) >> 16;          // low half  (elem 0)
    ub = (ub + 0x7fffu + ((ub >> 16) & 1u)) & 0xffff0000u;  // high half (elem 1)
    return ua | ub;
}
static __device__ __forceinline__ float bflo(uint32 w) { return __uint_as_float(w << 16); }
static __device__ __forceinline__ float bfhi(uint32 w) { return __uint_as_float(w & 0xffff0000u); }

// ---------------------------------------------------------------------------
// xbf[n][cp] = packed bf16 pair of x[n][2cp..2cp+1]  (cp = 0..31)
// ---------------------------------------------------------------------------
__global__ __launch_bounds__(256) void xbf_k(
    const float* __restrict__ x, uint32* __restrict__ xbf, int n2)
{
    const int i = blockIdx.x * 256 + threadIdx.x;
    if (i < n2) {
        const float2 v = ((const float2*)x)[i];
        xbf[i] = packbf(v.x, v.y);
    }
}

// ---------------------------------------------------------------------------
// Histogram over key = dst*8 + rel  (counts live in `start`, pre-zeroed)
// ---------------------------------------------------------------------------
__global__ __launch_bounds__(256) void hist_k(
    const int* __restrict__ ei, const int* __restrict__ rel,
    int* __restrict__ cnt, int nE, int nT)
{
    for (int e = blockIdx.x * 256 + threadIdx.x; e < nE; e += nT)
        atomicAdd(&cnt[ei[nE + e] * NREL + rel[e]], 1);
}

// ---------------------------------------------------------------------------
// Multi-block exclusive scan: (1) per-block scan in place + block totals,
// (2) scan of totals, (3) add offsets + fill cursor + start[nK].
// ---------------------------------------------------------------------------
__global__ __launch_bounds__(1024) void scan1_k(
    int* __restrict__ start, int* __restrict__ partials, int nK)
{
    __shared__ int sh[1024];
    const int t = threadIdx.x;
    const int g = blockIdx.x * 1024 + t;
    const int v = (g < nK) ? start[g] : 0;
    sh[t] = v; __syncthreads();
    for (int off = 1; off < 1024; off <<= 1) {
        int add = (t >= off) ? sh[t - off] : 0;
        __syncthreads();
        sh[t] += add;
        __syncthreads();
    }
    start[g] = sh[t] - v;                       // exclusive within block
    if (t == 1023) partials[blockIdx.x] = sh[1023];
}

__global__ __launch_bounds__(512) void scan2_k(int* __restrict__ partials, int nP)
{
    __shared__ int sh[512];
    const int t = threadIdx.x;
    const int v = (t < nP) ? partials[t] : 0;
    sh[t] = v; __syncthreads();
    for (int off = 1; off < 512; off <<= 1) {
        int add = (t >= off) ? sh[t - off] : 0;
        __syncthreads();
        sh[t] += add;
        __syncthreads();
    }
    if (t < nP) partials[t] = sh[t] - v;        // exclusive
}

__global__ __launch_bounds__(1024) void scan3_k(
    int* __restrict__ start, const int* __restrict__ partials,
    int* __restrict__ cursor, int nK)
{
    const int g = blockIdx.x * 1024 + threadIdx.x;
    if (g <= nK) {
        const int s = start[g] + partials[blockIdx.x];
        start[g] = s;
        if (g < nK) cursor[g] = s;
    }
}

// ---------------------------------------------------------------------------
// Reorder: sorted[pos] = src, bucketed by key.
// ---------------------------------------------------------------------------
__global__ __launch_bounds__(256) void reorder_k(
    const int* __restrict__ ei, const int* __restrict__ rel,
    int* __restrict__ cursor, int* __restrict__ sorted, int nE, int nT)
{
    for (int e = blockIdx.x * 256 + threadIdx.x; e < nE; e += nT) {
        const int key = ei[nE + e] * NREL + rel[e];
        const int pos = atomicAdd(&cursor[key], 1);
        sorted[pos] = ei[e];
    }
}

// ---------------------------------------------------------------------------
// Aggregate v2: one wave per dst node. Lanes 0-31 / 32-63 split each rel
// segment's edge list (even/odd j); lane%32 = channel pair (bf16 x rows,
// one 128B line per edge). Manual 2-deep unroll -> ~4 loads in flight per
// wave. Combine halves with shfl_xor(32); lanes 0-31 store the A row.
// ---------------------------------------------------------------------------
__global__ __launch_bounds__(256) void agg_k(
    const uint32* __restrict__ xbf, const int* __restrict__ start,
    const int* __restrict__ sorted, uint32* __restrict__ A, int nN)
{
    const int n = (int)((blockIdx.x * 256u + threadIdx.x) >> 6);
    if (n >= nN) return;
    const int l32  = threadIdx.x & 31;
    const int half = (threadIdx.x >> 5) & 1;
    const int kb   = n * NREL;

    int s = start[kb];
    #pragma unroll 1
    for (int r = 0; r < NREL; ++r) {
        const int e = start[kb + r + 1];
        float a0 = 0.f, a1 = 0.f;
        int j = s + half;
        for (; j + 2 < e; j += 4) {
            const uint32 u0 = xbf[(size_t)sorted[j]     * 32 + l32];
            const uint32 u1 = xbf[(size_t)sorted[j + 2] * 32 + l32];
            a0 += bflo(u0); a1 += bfhi(u0);
            a0 += bflo(u1); a1 += bfhi(u1);
        }
        if (j < e) {
            const uint32 u = xbf[(size_t)sorted[j] * 32 + l32];
            a0 += bflo(u); a1 += bfhi(u);
        }
        a0 += __shfl_xor(a0, 32);
        a1 += __shfl_xor(a1, 32);
        if (half == 0)
            A[(size_t)(kb + r) * 32 + l32] = packbf(a0, a1);
        s = e;
    }
}

// ---------------------------------------------------------------------------
// GEMM: out[nN,64] = A[nN,512](bf16) @ Wf[512,64](fp32, == W viewed flat).
// 64x64 output tile per block, K staged in chunks of 128. LDS 64 KB.
// ---------------------------------------------------------------------------
__global__ __launch_bounds__(256, 2) void gemm_k(
    const uint32* __restrict__ A, const float* __restrict__ Wf,
    float* __restrict__ out, int nN)
{
    __shared__ float AT[128 * 64];   // [k][n] 32 KB
    __shared__ float WC[128 * 64];   // [k][h] 32 KB

    const int t      = threadIdx.x;
    const int n_base = blockIdx.x * 64;
    const int n_l    = t & 63;
    const int q      = t >> 6;            // 0..3 -> k sub-block of 32
    const int tn     = t >> 4;            // 0..15 node quad
    const int th     = t & 15;            // 0..15 h quad

    float acc[4][4];
    #pragma unroll
    for (int a = 0; a < 4; ++a)
        #pragma unroll
        for (int b = 0; b < 4; ++b) acc[a][b] = 0.f;

    for (int kc = 0; kc < 512; kc += 128) {
        {
            const int n  = n_base + n_l;
            const int kb = q * 32;
            if (n < nN) {
                const uint32* ap = A + (size_t)n * 256 + ((kc + kb) >> 1);
                #pragma unroll
                for (int m = 0; m < 4; ++m) {
                    const uint4 u = *(const uint4*)(ap + m * 4);   // 8 bf16
                    const int kk = kb + m * 8;
                    AT[(kk + 0) * 64 + n_l] = bflo(u.x);
                    AT[(kk + 1) * 64 + n_l] = bfhi(u.x);
                    AT[(kk + 2) * 64 + n_l] = bflo(u.y);
                    AT[(kk + 3) * 64 + n_l] = bfhi(u.y);
                    AT[(kk + 4) * 64 + n_l] = bflo(u.z);
                    AT[(kk + 5) * 64 + n_l] = bfhi(u.z);
                    AT[(kk + 6) * 64 + n_l] = bflo(u.w);
                    AT[(kk + 7) * 64 + n_l] = bfhi(u.w);
                }
            } else {
                #pragma unroll
                for (int m = 0; m < 32; ++m) AT[(kb + m) * 64 + n_l] = 0.f;
            }
        }
        {
            const float* wsrc = Wf + (kc << 6);
            #pragma unroll
            for (int j = 0; j < 8; ++j) {
                const int idx = (t << 2) + (j << 10);
                *(float4*)(WC + idx) = *(const float4*)(wsrc + idx);
            }
        }
        __syncthreads();

        #pragma unroll 8
        for (int i = 0; i < 128; ++i) {
            const float4 av = *(const float4*)(AT + i * 64 + (tn << 2));
            const float4 bv = *(const float4*)(WC + i * 64 + (th << 2));
            acc[0][0] += av.x * bv.x; acc[0][1] += av.x * bv.y;
            acc[0][2] += av.x * bv.z; acc[0][3] += av.x * bv.w;
            acc[1][0] += av.y * bv.x; acc[1][1] += av.y * bv.y;
            acc[1][2] += av.y * bv.z; acc[1][3] += av.y * bv.w;
            acc[2][0] += av.z * bv.x; acc[2][1] += av.z * bv.y;
            acc[2][2] += av.z * bv.z; acc[2][3] += av.z * bv.w;
            acc[3][0] += av.w * bv.x; acc[3][1] += av.w * bv.y;
            acc[3][2] += av.w * bv.z; acc[3][3] += av.w * bv.w;
        }
        __syncthreads();
    }

    #pragma unroll
    for (int dn = 0; dn < 4; ++dn) {
        const int n = n_base + (tn << 2) + dn;
        if (n < nN) {
            float4 o;
            o.x = acc[dn][0]; o.y = acc[dn][1]; o.z = acc[dn][2]; o.w = acc[dn][3];
            *(float4*)(out + (size_t)n * CH + (th << 2)) = o;
        }
    }
}

// ---------------------------------------------------------------------------
// Fallback (ws too small): per-edge direct with atomics.
// ---------------------------------------------------------------------------
__global__ __launch_bounds__(256) void rgcn_direct_kernel(
    const float* __restrict__ x, const float* __restrict__ W,
    const int* __restrict__ ei, const int* __restrict__ rel,
    float* __restrict__ out, int nE, int nWaves)
{
    const int w    = (int)((blockIdx.x * 256u + threadIdx.x) >> 6);
    const int lane = threadIdx.x & 63;

    for (int e = w; e < nE; e += nWaves) {
        const int src = ei[e];
        const int dst = ei[nE + e];
        const int r   = rel[e];
        const float* xrow = x + (size_t)src * CH;
        const float* wcol = W + ((size_t)r << 12) + lane;
        float acc = 0.f;
        #pragma unroll
        for (int i = 0; i < CH; ++i) acc += xrow[i] * wcol[i * CH];
        atomicAdd(out + (size_t)dst * CH + lane, acc);
    }
}

static inline size_t align256(size_t v) { return (v + 255) & ~(size_t)255; }

extern "C" void kernel_launch(void* const* d_in, const int* in_sizes, int n_in,
                              void* d_out, int out_size, void* d_ws, size_t ws_size,
                              hipStream_t stream) {
    const float* x   = (const float*)d_in[0];
    const float* W   = (const float*)d_in[1];
    const int*   ei  = (const int*)d_in[2];
    const int*   rel = (const int*)d_in[3];
    float*       out = (float*)d_out;

    const int nN = in_sizes[0] / CH;   // 50000
    const int nE = in_sizes[3];        // 1000000
    const int nK = nN * NREL;          // 400000
    const int S1B = (nK + 1023) / 1024;   // scan blocks (391)

    // Workspace layout
    const size_t sz_A      = align256((size_t)nK * 32 * sizeof(uint32));  // 51.2 MB bf16
    const size_t sz_xbf    = align256((size_t)nN * 32 * sizeof(uint32));  // 6.4 MB bf16
    const size_t sz_start  = align256((size_t)(nK + 1024) * sizeof(int));
    const size_t sz_cursor = align256((size_t)(nK + 1) * sizeof(int));
    const size_t sz_sorted = align256((size_t)nE * sizeof(int));
    const size_t sz_part   = align256(512 * sizeof(int));
    const size_t need = sz_A + sz_xbf + sz_start + sz_cursor + sz_sorted + sz_part;

    if (ws_size >= need && S1B <= 512) {
        char* p = (char*)d_ws;
        uint32* A      = (uint32*)p;  p += sz_A;
        uint32* xbf    = (uint32*)p;  p += sz_xbf;
        int*    start  = (int*)p;     p += sz_start;
        int*    cursor = (int*)p;     p += sz_cursor;
        int*    sorted = (int*)p;     p += sz_sorted;
        int*    part   = (int*)p;

        hipMemsetAsync(start, 0, sz_start, stream);

        const int n2 = nN * 32;
        xbf_k<<<(n2 + 255) / 256, 256, 0, stream>>>(x, xbf, n2);

        const int sb = 1024;
        hist_k<<<sb, 256, 0, stream>>>(ei, rel, start, nE, sb * 256);
        scan1_k<<<S1B, 1024, 0, stream>>>(start, part, nK);
        scan2_k<<<1, 512, 0, stream>>>(part, S1B);
        scan3_k<<<S1B, 1024, 0, stream>>>(start, part, cursor, nK);
        reorder_k<<<sb, 256, 0, stream>>>(ei, rel, cursor, sorted, nE, sb * 256);

        const int aggBlocks = (nN + 3) / 4;     // 1 node/wave, 4 waves/block
        agg_k<<<aggBlocks, 256, 0, stream>>>(xbf, start, sorted, A, nN);

        gemm_k<<<(nN + 63) / 64, 256, 0, stream>>>(A, W, out, nN);
    } else {
        hipMemsetAsync(out, 0, (size_t)out_size * sizeof(float), stream);
        const int blocks = 2048;
        const int nWaves = blocks * (256 / 64);
        rgcn_direct_kernel<<<blocks, 256, 0, stream>>>(x, W, ei, rel, out, nE, nWaves);
    }
}

// Round 6
// 182.404 us; speedup vs baseline: 4.1832x; 1.4319x over previous
//
#include <hip/hip_runtime.h>
#include <hip/hip_bf16.h>

#define NREL 8
#define CH   64   // IN_CH == HID_CH == 64

typedef unsigned int uint32;

// ---- bf16 helpers (RNE) ----------------------------------------------------
static __device__ __forceinline__ uint32 packbf(float a, float b) {
    uint32 ua = __float_as_uint(a), ub = __float_as_uint(b);
    ua = (ua + 0x7fffu + ((ua >> 16) & 1u)) >> 16;          // low half  (elem 0)
    ub = (ub + 0x7fffu + ((ub >> 16) & 1u)) & 0xffff0000u;  // high half (elem 1)
    return ua | ub;
}
static __device__ __forceinline__ float bflo(uint32 w) { return __uint_as_float(w << 16); }
static __device__ __forceinline__ float bfhi(uint32 w) { return __uint_as_float(w & 0xffff0000u); }

// ---------------------------------------------------------------------------
// xbf[n][cp] = packed bf16 pair of x[n][2cp..2cp+1]  (cp = 0..31)
// ---------------------------------------------------------------------------
__global__ __launch_bounds__(256) void xbf_k(
    const float* __restrict__ x, uint32* __restrict__ xbf, int n2)
{
    const int i = blockIdx.x * 256 + threadIdx.x;
    if (i < n2) {
        const float2 v = ((const float2*)x)[i];
        xbf[i] = packbf(v.x, v.y);
    }
}

// ---------------------------------------------------------------------------
// Coarse histogram over c = dst>>8 (NC buckets). LDS-staged, few global atomics.
// ---------------------------------------------------------------------------
__global__ __launch_bounds__(256) void chist_k(
    const int* __restrict__ ei, int* __restrict__ ccnt, int nE, int nT)
{
    __shared__ int h[256];
    h[threadIdx.x] = 0;
    __syncthreads();
    for (int e = blockIdx.x * 256 + threadIdx.x; e < nE; e += nT)
        atomicAdd(&h[ei[nE + e] >> 8], 1);
    __syncthreads();
    const int c = threadIdx.x;
    if (h[c]) atomicAdd(&ccnt[c], h[c]);
}

// ---------------------------------------------------------------------------
// Coarse exclusive scan (NC <= 256), fills cbase[0..NC] and ccur.
// ---------------------------------------------------------------------------
__global__ __launch_bounds__(256) void cscan_k(
    const int* __restrict__ ccnt, int* __restrict__ cbase,
    int* __restrict__ ccur, int NC)
{
    __shared__ int sc[256];
    const int t = threadIdx.x;
    const int v = (t < NC) ? ccnt[t] : 0;
    sc[t] = v;
    __syncthreads();
    for (int off = 1; off < 256; off <<= 1) {
        int add = (t >= off) ? sc[t - off] : 0;
        __syncthreads();
        sc[t] += add;
        __syncthreads();
    }
    const int ex = sc[t] - v;
    if (t < NC) { cbase[t] = ex; ccur[t] = ex; }
    if (t == 255) cbase[NC] = sc[255];
}

// ---------------------------------------------------------------------------
// Coarse binning: per 2048-edge chunk, stage entries in LDS, count per coarse
// bucket, reserve contiguous runs via one global atomic per bucket, write runs.
// Entry pack: (dlow<<24)|(rel<<16)|src  (dlow = dst&255, src < 65536).
// ---------------------------------------------------------------------------
__global__ __launch_bounds__(256) void bin_k(
    const int* __restrict__ ei, const int* __restrict__ rel,
    int* __restrict__ ccur, uint32* __restrict__ binned, int nE)
{
    __shared__ uint32        ent[2048];
    __shared__ unsigned char cid[2048];
    __shared__ int lh[256], lb[256], lc[256];

    const int t = threadIdx.x;
    lh[t] = 0;
    __syncthreads();

    const int base = blockIdx.x * 2048;
    #pragma unroll
    for (int i = 0; i < 8; ++i) {
        const int idx = t + i * 256;
        const int e   = base + idx;
        if (e < nE) {
            const int dst = ei[nE + e];
            ent[idx] = ((uint32)(dst & 255) << 24) | ((uint32)rel[e] << 16) | (uint32)ei[e];
            const int c = dst >> 8;
            cid[idx] = (unsigned char)c;
            atomicAdd(&lh[c], 1);
        } else {
            cid[idx] = 255;   // sentinel (valid: NC <= 254 guard in launcher)
        }
    }
    __syncthreads();

    if (lh[t]) lb[t] = atomicAdd(&ccur[t], lh[t]);
    lc[t] = 0;
    __syncthreads();

    #pragma unroll
    for (int i = 0; i < 8; ++i) {
        const int idx = t + i * 256;
        const int c   = cid[idx];
        if (c != 255) {
            const int off = atomicAdd(&lc[c], 1);
            binned[lb[c] + off] = ent[idx];
        }
    }
}

// ---------------------------------------------------------------------------
// Fine sort within one coarse bucket (keyspace 2048 = dlow*8+rel), all in LDS.
// Emits global start[] (coalesced) and sorted[] (src), block-local writes.
// ---------------------------------------------------------------------------
__global__ __launch_bounds__(1024) void fsort_k(
    const uint32* __restrict__ binned, const int* __restrict__ cbase,
    int* __restrict__ start, int* __restrict__ sorted, int NC)
{
    __shared__ int fh[2048], fex[2048], fcur[2048], sc[1024];
    const int c  = blockIdx.x;
    const int t  = threadIdx.x;
    const int n0 = cbase[c];
    const int n1 = cbase[c + 1];

    fh[t] = 0; fh[t + 1024] = 0;
    __syncthreads();

    for (int j = n0 + t; j < n1; j += 1024) {
        const uint32 en = binned[j];
        atomicAdd(&fh[((en >> 24) << 3) | ((en >> 16) & 7)], 1);
    }
    __syncthreads();

    // exclusive scan over 2048 via pairwise + Hillis-Steele(1024)
    const int a = fh[2 * t], b = fh[2 * t + 1];
    sc[t] = a + b;
    __syncthreads();
    for (int off = 1; off < 1024; off <<= 1) {
        int add = (t >= off) ? sc[t - off] : 0;
        __syncthreads();
        sc[t] += add;
        __syncthreads();
    }
    const int ep = sc[t] - (a + b);
    fex[2 * t] = ep; fex[2 * t + 1] = ep + a;
    __syncthreads();

    fcur[t] = fex[t]; fcur[t + 1024] = fex[t + 1024];
    {
        const int k0 = c << 11;
        start[k0 + t]        = n0 + fex[t];
        start[k0 + t + 1024] = n0 + fex[t + 1024];
    }
    if (c == NC - 1 && t == 0) start[NC << 11] = n1;
    __syncthreads();

    for (int j = n0 + t; j < n1; j += 1024) {
        const uint32 en = binned[j];
        const int fk  = ((en >> 24) << 3) | ((en >> 16) & 7);
        const int off = atomicAdd(&fcur[fk], 1);
        sorted[n0 + off] = (int)(en & 0xFFFFu);
    }
}

// ---------------------------------------------------------------------------
// Aggregate: one wave per dst node. Halves split each rel segment (even/odd);
// lane%32 = channel pair. 2-deep unroll for MLP; shfl_xor(32) combine.
// ---------------------------------------------------------------------------
__global__ __launch_bounds__(256) void agg_k(
    const uint32* __restrict__ xbf, const int* __restrict__ start,
    const int* __restrict__ sorted, uint32* __restrict__ A, int nN)
{
    const int n = (int)((blockIdx.x * 256u + threadIdx.x) >> 6);
    if (n >= nN) return;
    const int l32  = threadIdx.x & 31;
    const int half = (threadIdx.x >> 5) & 1;
    const int kb   = n * NREL;

    int s = start[kb];
    #pragma unroll 1
    for (int r = 0; r < NREL; ++r) {
        const int e = start[kb + r + 1];
        float a0 = 0.f, a1 = 0.f;
        int j = s + half;
        for (; j + 2 < e; j += 4) {
            const uint32 u0 = xbf[(size_t)sorted[j]     * 32 + l32];
            const uint32 u1 = xbf[(size_t)sorted[j + 2] * 32 + l32];
            a0 += bflo(u0); a1 += bfhi(u0);
            a0 += bflo(u1); a1 += bfhi(u1);
        }
        if (j < e) {
            const uint32 u = xbf[(size_t)sorted[j] * 32 + l32];
            a0 += bflo(u); a1 += bfhi(u);
        }
        a0 += __shfl_xor(a0, 32);
        a1 += __shfl_xor(a1, 32);
        if (half == 0)
            A[(size_t)(kb + r) * 32 + l32] = packbf(a0, a1);
        s = e;
    }
}

// ---------------------------------------------------------------------------
// GEMM: out[nN,64] = A[nN,512](bf16) @ Wf[512,64](fp32). 64x64 tile, K=128 chunks.
// ---------------------------------------------------------------------------
__global__ __launch_bounds__(256, 2) void gemm_k(
    const uint32* __restrict__ A, const float* __restrict__ Wf,
    float* __restrict__ out, int nN)
{
    __shared__ float AT[128 * 64];   // [k][n] 32 KB
    __shared__ float WC[128 * 64];   // [k][h] 32 KB

    const int t      = threadIdx.x;
    const int n_base = blockIdx.x * 64;
    const int n_l    = t & 63;
    const int q      = t >> 6;
    const int tn     = t >> 4;
    const int th     = t & 15;

    float acc[4][4];
    #pragma unroll
    for (int a = 0; a < 4; ++a)
        #pragma unroll
        for (int b = 0; b < 4; ++b) acc[a][b] = 0.f;

    for (int kc = 0; kc < 512; kc += 128) {
        {
            const int n  = n_base + n_l;
            const int kb = q * 32;
            if (n < nN) {
                const uint32* ap = A + (size_t)n * 256 + ((kc + kb) >> 1);
                #pragma unroll
                for (int m = 0; m < 4; ++m) {
                    const uint4 u = *(const uint4*)(ap + m * 4);   // 8 bf16
                    const int kk = kb + m * 8;
                    AT[(kk + 0) * 64 + n_l] = bflo(u.x);
                    AT[(kk + 1) * 64 + n_l] = bfhi(u.x);
                    AT[(kk + 2) * 64 + n_l] = bflo(u.y);
                    AT[(kk + 3) * 64 + n_l] = bfhi(u.y);
                    AT[(kk + 4) * 64 + n_l] = bflo(u.z);
                    AT[(kk + 5) * 64 + n_l] = bfhi(u.z);
                    AT[(kk + 6) * 64 + n_l] = bflo(u.w);
                    AT[(kk + 7) * 64 + n_l] = bfhi(u.w);
                }
            } else {
                #pragma unroll
                for (int m = 0; m < 32; ++m) AT[(kb + m) * 64 + n_l] = 0.f;
            }
        }
        {
            const float* wsrc = Wf + (kc << 6);
            #pragma unroll
            for (int j = 0; j < 8; ++j) {
                const int idx = (t << 2) + (j << 10);
                *(float4*)(WC + idx) = *(const float4*)(wsrc + idx);
            }
        }
        __syncthreads();

        #pragma unroll 8
        for (int i = 0; i < 128; ++i) {
            const float4 av = *(const float4*)(AT + i * 64 + (tn << 2));
            const float4 bv = *(const float4*)(WC + i * 64 + (th << 2));
            acc[0][0] += av.x * bv.x; acc[0][1] += av.x * bv.y;
            acc[0][2] += av.x * bv.z; acc[0][3] += av.x * bv.w;
            acc[1][0] += av.y * bv.x; acc[1][1] += av.y * bv.y;
            acc[1][2] += av.y * bv.z; acc[1][3] += av.y * bv.w;
            acc[2][0] += av.z * bv.x; acc[2][1] += av.z * bv.y;
            acc[2][2] += av.z * bv.z; acc[2][3] += av.z * bv.w;
            acc[3][0] += av.w * bv.x; acc[3][1] += av.w * bv.y;
            acc[3][2] += av.w * bv.z; acc[3][3] += av.w * bv.w;
        }
        __syncthreads();
    }

    #pragma unroll
    for (int dn = 0; dn < 4; ++dn) {
        const int n = n_base + (tn << 2) + dn;
        if (n < nN) {
            float4 o;
            o.x = acc[dn][0]; o.y = acc[dn][1]; o.z = acc[dn][2]; o.w = acc[dn][3];
            *(float4*)(out + (size_t)n * CH + (th << 2)) = o;
        }
    }
}

// ---------------------------------------------------------------------------
// Fallback: per-edge direct with atomics.
// ---------------------------------------------------------------------------
__global__ __launch_bounds__(256) void rgcn_direct_kernel(
    const float* __restrict__ x, const float* __restrict__ W,
    const int* __restrict__ ei, const int* __restrict__ rel,
    float* __restrict__ out, int nE, int nWaves)
{
    const int w    = (int)((blockIdx.x * 256u + threadIdx.x) >> 6);
    const int lane = threadIdx.x & 63;

    for (int e = w; e < nE; e += nWaves) {
        const int src = ei[e];
        const int dst = ei[nE + e];
        const int r   = rel[e];
        const float* xrow = x + (size_t)src * CH;
        const float* wcol = W + ((size_t)r << 12) + lane;
        float acc = 0.f;
        #pragma unroll
        for (int i = 0; i < CH; ++i) acc += xrow[i] * wcol[i * CH];
        atomicAdd(out + (size_t)dst * CH + lane, acc);
    }
}

static inline size_t align256(size_t v) { return (v + 255) & ~(size_t)255; }

extern "C" void kernel_launch(void* const* d_in, const int* in_sizes, int n_in,
                              void* d_out, int out_size, void* d_ws, size_t ws_size,
                              hipStream_t stream) {
    const float* x   = (const float*)d_in[0];
    const float* W   = (const float*)d_in[1];
    const int*   ei  = (const int*)d_in[2];
    const int*   rel = (const int*)d_in[3];
    float*       out = (float*)d_out;

    const int nN = in_sizes[0] / CH;   // 50000
    const int nE = in_sizes[3];        // 1000000
    const int nK = nN * NREL;          // 400000
    const int NC = (nN + 255) >> 8;    // 196 coarse buckets

    // Workspace layout
    const size_t sz_A      = align256((size_t)nK * 32 * sizeof(uint32));        // 51.2 MB
    const size_t sz_xbf    = align256((size_t)nN * 32 * sizeof(uint32));        // 6.4 MB
    const size_t sz_start  = align256(((size_t)NC * 2048 + 2) * sizeof(int));   // 1.6 MB
    const size_t sz_binned = align256((size_t)nE * sizeof(uint32));             // 4 MB
    const size_t sz_sorted = align256((size_t)nE * sizeof(int));                // 4 MB
    const size_t sz_ccnt   = align256(256 * sizeof(int));
    const size_t sz_cbase  = align256(257 * sizeof(int));
    const size_t sz_ccur   = align256(256 * sizeof(int));
    const size_t need = sz_A + sz_xbf + sz_start + sz_binned + sz_sorted +
                        sz_ccnt + sz_cbase + sz_ccur;

    if (ws_size >= need && nN <= 65024 && NC <= 254) {
        char* p = (char*)d_ws;
        uint32* A      = (uint32*)p;  p += sz_A;
        uint32* xbf    = (uint32*)p;  p += sz_xbf;
        int*    start  = (int*)p;     p += sz_start;
        uint32* binned = (uint32*)p;  p += sz_binned;
        int*    sorted = (int*)p;     p += sz_sorted;
        int*    ccnt   = (int*)p;     p += sz_ccnt;
        int*    cbase  = (int*)p;     p += sz_cbase;
        int*    ccur   = (int*)p;

        hipMemsetAsync(ccnt, 0, 256 * sizeof(int), stream);

        const int n2 = nN * 32;
        xbf_k<<<(n2 + 255) / 256, 256, 0, stream>>>(x, xbf, n2);

        chist_k<<<256, 256, 0, stream>>>(ei, ccnt, nE, 256 * 256);
        cscan_k<<<1, 256, 0, stream>>>(ccnt, cbase, ccur, NC);
        bin_k<<<(nE + 2047) / 2048, 256, 0, stream>>>(ei, rel, ccur, binned, nE);
        fsort_k<<<NC, 1024, 0, stream>>>(binned, cbase, start, sorted, NC);

        const int aggBlocks = (nN + 3) / 4;
        agg_k<<<aggBlocks, 256, 0, stream>>>(xbf, start, sorted, A, nN);

        gemm_k<<<(nN + 63) / 64, 256, 0, stream>>>(A, W, out, nN);
    } else {
        hipMemsetAsync(out, 0, (size_t)out_size * sizeof(float), stream);
        const int blocks = 2048;
        const int nWaves = blocks * (256 / 64);
        rgcn_direct_kernel<<<blocks, 256, 0, stream>>>(x, W, ei, rel, out, nE, nWaves);
    }
}